// Round 11
// baseline (241.884 us; speedup 1.0000x reference)
//
#include <hip/hip_runtime.h>
#include <hip/hip_bf16.h>
#include <math.h>

// SPDNet collapsed: ReEig layers are no-ops (spectrum in [0.1, ~4.3] by
// Rayleigh interlacing through orthonormal-column BiMaps), so
//   X3 = (w1 w2 w3)^T X (w1 w2 w3);  out = vec(logm(X3)) @ fc
// logm via degree-28 Chebyshev matrix-Clenshaw on B=(X3-mI)/h, [0.0995,4.8].
// R11: k_bimap rewritten for CONTIGUOUS X streaming (R10 counters: 974 GB/s,
//   all pipes idle -> strided k-tile reads were the cap). Row-tiles of 64:
//   stage 64 full rows (contiguous 100KB) as bf16 h/l in LDS [64][424]
//   (848B stride: 2-way bank alias = free, 16B aligned); phase-1 full-K MFMA
//   per row-tile; phase-2 X3 += W^T Y_rowblock incrementally from small Yt.
//   W padded to K=448 (phase-2 i-index reaches 447 on last tile; zeros kill
//   the garbage rows). k_logcheb unchanged (verified R9/R10).
// ws layout (floats): T1 @0 (40000), X3 @40000 (665600),
//   Wth @705600 (ushort[64*448]), Wtl @719936. Total ~2.94 MB.

#define CM 2.44975f
#define CH 2.35025f
#define CM_D 2.44975
#define CH_D 2.35025
#define DEG 28
#define PI_D 3.14159265358979323846
#define XS 424   // X LDS row stride (ushorts)
#define YS 72    // Yt LDS row stride (ushorts)
#define WKS 448  // Wth/Wtl k stride

typedef __attribute__((ext_vector_type(8))) short short8;
typedef __attribute__((ext_vector_type(4))) float f32x4;

struct ChebC { float c[32]; };

__device__ __forceinline__ ushort bfrne(float x) {
    return __builtin_bit_cast(unsigned short, __float2bfloat16(x));
}
__device__ __forceinline__ float bff(ushort h) {
    return __uint_as_float(((unsigned)h) << 16);
}

__global__ void k_mm(const float* __restrict__ A, const float* __restrict__ B,
                     float* __restrict__ C, int M, int K, int N) {
    int e = blockIdx.x * blockDim.x + threadIdx.x;
    if (e >= M * N) return;
    int r = e / N, c = e % N;
    float acc = 0.f;
    for (int k = 0; k < K; ++k) acc = fmaf(A[r * K + k], B[k * N + c], acc);
    C[e] = acc;
}

// Fused: W = T1 @ w3 (400x100 @ 100x50), transposed + bf16x2 split.
// Wth/Wtl[64][448] c-major, zeros outside [50][400].
__global__ void k_wprep(const float* __restrict__ T1, const float* __restrict__ w3,
                        ushort* __restrict__ Wth, ushort* __restrict__ Wtl) {
    int e = blockIdx.x * blockDim.x + threadIdx.x;
    if (e >= 64 * WKS) return;
    int c = e / WKS, k = e % WKS;
    float v = 0.f;
    if (c < 50 && k < 400)
        for (int j = 0; j < 100; ++j) v = fmaf(T1[k * 100 + j], w3[j * 50 + c], v);
    const ushort h = bfrne(v);
    Wth[e] = h;
    Wtl[e] = bfrne(v - bff(h));
}

// One 512-thread (8-wave) block per batch. MFMA bf16x2, contiguous streaming.
// Per 64-row tile rt: stage X[i0..i0+63][0:400] (contiguous) as bf16 h/l;
// phase 1: Y rows = Xtile @ W (wave = (m=w>>1, npair=(w&1)*2), full K);
// write Y D-frags transposed to Yt[64][72] bf16 h/l;
// phase 2: X3 += W^T[, i0..i0+63] @ Ytile (same wave->tile map), acc held.
// Garbage/zero rows beyond 400 are annihilated by W's zero k-padding.
__global__ __launch_bounds__(512) void k_bimap(const float* __restrict__ X,
                                               const ushort* __restrict__ Wth,
                                               const ushort* __restrict__ Wtl,
                                               float* __restrict__ X3) {
    __shared__ ushort XhL[64 * XS];  // 54272 B
    __shared__ ushort XlL[64 * XS];  // 54272 B
    __shared__ ushort YtH[64 * YS];  // 9216 B
    __shared__ ushort YtL[64 * YS];  // 9216 B  (total 126976 B)

    const int tid = threadIdx.x;
    const int w = tid >> 6, l = tid & 63;
    const int lr = l & 15, lg = l >> 4;
    const int b = blockIdx.x;
    const float* __restrict__ Xb = X + (size_t)b * 160000;

    const int m  = w >> 1;        // tile-row index (phase1 local rows / phase2 c-rows)
    const int np = (w & 1) * 2;   // n-pair base (phase1 Y-cols / phase2 c'-cols)

    // zero X pad cols 400..423 once (never written by staging; NaN-safety)
    for (int e = tid; e < 64 * 24; e += 512) {
        const int r = e / 24, c = 400 + e % 24;
        XhL[r * XS + c] = 0;
        XlL[r * XS + c] = 0;
    }

    f32x4 p2[2] = {(f32x4){0.f, 0.f, 0.f, 0.f}, (f32x4){0.f, 0.f, 0.f, 0.f}};

    // prefetch tile 0 (rows 0..63): 6400 float4, fully in-bounds
    float4 pf[13];
    #pragma unroll
    for (int j = 0; j < 13; ++j) {
        const int e = tid + 512 * j;
        pf[j] = make_float4(0.f, 0.f, 0.f, 0.f);
        if (e < 6400) pf[j] = *(const float4*)(Xb + (size_t)e * 4);
    }

    for (int rt = 0; rt < 7; ++rt) {
        const int i0 = rt * 64;
        // (A) write staged tile (consumes pf)
        #pragma unroll
        for (int j = 0; j < 13; ++j) {
            const int e = tid + 512 * j;
            if (e < 6400) {
                const int row = e / 100;
                const int col = (e % 100) * 4;
                const float vv[4] = {pf[j].x, pf[j].y, pf[j].z, pf[j].w};
                ushort h[4], lo[4];
                #pragma unroll
                for (int i = 0; i < 4; ++i) {
                    h[i] = bfrne(vv[i]);
                    lo[i] = bfrne(vv[i] - bff(h[i]));
                }
                *(ushort4*)&XhL[row * XS + col] = make_ushort4(h[0], h[1], h[2], h[3]);
                *(ushort4*)&XlL[row * XS + col] = make_ushort4(lo[0], lo[1], lo[2], lo[3]);
            }
        }
        __syncthreads();  // B1: X tile visible; prior phase-2 Yt readers done
        // (C) prefetch next tile (zero-guarded: rows >= 400 stay exact 0)
        if (rt < 6) {
            const int i0n = i0 + 64;
            #pragma unroll
            for (int j = 0; j < 13; ++j) {
                const int e = tid + 512 * j;
                if (e < 6400) {
                    const size_t gf = (size_t)i0n * 400 + (size_t)e * 4;
                    pf[j] = (gf < 160000) ? *(const float4*)(Xb + gf)
                                          : make_float4(0.f, 0.f, 0.f, 0.f);
                }
            }
        }
        // (D) phase 1: Y[tile] = Xtile @ W, full K=400 (13 ks)
        f32x4 p1[2] = {(f32x4){0.f, 0.f, 0.f, 0.f}, (f32x4){0.f, 0.f, 0.f, 0.f}};
        for (int ks = 0; ks < 13; ++ks) {
            const int ko = ks * 32 + lg * 8;
            const short8 Ah = *(const short8*)&XhL[(m * 16 + lr) * XS + ko];
            const short8 Al = *(const short8*)&XlL[(m * 16 + lr) * XS + ko];
            #pragma unroll
            for (int t = 0; t < 2; ++t) {
                const int c = (np + t) * 16 + lr;
                const short8 Bh = *(const short8*)&Wth[c * WKS + ko];
                const short8 Bl = *(const short8*)&Wtl[c * WKS + ko];
                p1[t] = __builtin_amdgcn_mfma_f32_16x16x32_bf16(Ah, Bh, p1[t], 0, 0, 0);
                p1[t] = __builtin_amdgcn_mfma_f32_16x16x32_bf16(Ah, Bl, p1[t], 0, 0, 0);
                p1[t] = __builtin_amdgcn_mfma_f32_16x16x32_bf16(Al, Bh, p1[t], 0, 0, 0);
            }
        }
        __syncthreads();  // B2: X readers done (safe to re-stage next iter); Yt writable
        // (E) write Y D-frags transposed into Yt (bf16 h/l)
        #pragma unroll
        for (int t = 0; t < 2; ++t) {
            const int c = (np + t) * 16 + lr;
            const int ii = m * 16 + lg * 4;
            ushort h[4], lo[4];
            #pragma unroll
            for (int r = 0; r < 4; ++r) {
                h[r] = bfrne(p1[t][r]);
                lo[r] = bfrne(p1[t][r] - bff(h[r]));
            }
            *(ushort4*)&YtH[c * YS + ii] = make_ushort4(h[0], h[1], h[2], h[3]);
            *(ushort4*)&YtL[c * YS + ii] = make_ushort4(lo[0], lo[1], lo[2], lo[3]);
        }
        __syncthreads();  // B3: Yt visible
        // (F) phase 2: X3 += W^T[:, i0..i0+63] @ Ytile (k = i, 2 ks of 32)
        #pragma unroll
        for (int ks2 = 0; ks2 < 2; ++ks2) {
            const int kk = i0 + ks2 * 32 + lg * 8;      // <= 447 < WKS
            const int lo2 = ks2 * 32 + lg * 8;
            const short8 Ah2 = *(const short8*)&Wth[(m * 16 + lr) * WKS + kk];
            const short8 Al2 = *(const short8*)&Wtl[(m * 16 + lr) * WKS + kk];
            #pragma unroll
            for (int t = 0; t < 2; ++t) {
                const int cc = (np + t) * 16 + lr;
                const short8 Bh2 = *(const short8*)&YtH[cc * YS + lo2];
                const short8 Bl2 = *(const short8*)&YtL[cc * YS + lo2];
                p2[t] = __builtin_amdgcn_mfma_f32_16x16x32_bf16(Ah2, Bh2, p2[t], 0, 0, 0);
                p2[t] = __builtin_amdgcn_mfma_f32_16x16x32_bf16(Ah2, Bl2, p2[t], 0, 0, 0);
                p2[t] = __builtin_amdgcn_mfma_f32_16x16x32_bf16(Al2, Bh2, p2[t], 0, 0, 0);
            }
        }
        // next-iter (A) rewrites XhL (readers done at B2); (E) rewrites Yt
        // only after next B2, and this iter's F readers pass next B1 first.
    }

    float* __restrict__ dst = X3 + (size_t)b * 2600;
    #pragma unroll
    for (int t = 0; t < 2; ++t) {
        const int cc = (np + t) * 16 + lr;
        if (cc < 52) {
            #pragma unroll
            for (int r = 0; r < 4; ++r) {
                const int rr2 = m * 16 + lg * 4 + r;
                if (rr2 < 50) dst[rr2 * 52 + cc] = p2[t][r];
            }
        }
    }
}

// One 512-thread (8-wave) block per batch: L = p_DEG(B), MFMA Clenshaw.
// (verified R9/R10 at absmax 1.2e-4; unchanged)
__global__ __launch_bounds__(512) void k_logcheb(const float* __restrict__ X3,
                                                 const ChebC ccf,
                                                 const float* __restrict__ fc,
                                                 float* __restrict__ out) {
    __shared__ ushort ldsU[16384];  // 2 bufs x 2 lvl x 4096 (32 KB)
    __shared__ float Lf[50 * 56];
    __shared__ float red[512 * 7];
    const int tid = threadIdx.x;
    const int w = tid >> 6, l = tid & 63;
    const int lr = l & 15, lg = l >> 4;
    const int b = blockIdx.x;
    const float* __restrict__ src = X3 + (size_t)b * 2600;

    const int mrow = w >> 1;
    const int npair = (w & 1) * 2;

    short8 Ah[2], Al[2];
    {
        const int arow = mrow * 16 + lr;
        const float ih = 1.f / CH;
        #pragma unroll
        for (int ks = 0; ks < 2; ++ks) {
            float x[8];
            #pragma unroll
            for (int hf = 0; hf < 2; ++hf) {
                const int k0 = ks * 32 + lg * 8 + hf * 4;
                float4 v = make_float4(0.f, 0.f, 0.f, 0.f);
                if (arow < 50 && k0 < 52)
                    v = *(const float4*)(src + arow * 52 + k0);
                x[hf * 4 + 0] = v.x; x[hf * 4 + 1] = v.y;
                x[hf * 4 + 2] = v.z; x[hf * 4 + 3] = v.w;
            }
            short8 sh, sl;
            #pragma unroll
            for (int i = 0; i < 8; ++i) {
                const int k = ks * 32 + lg * 8 + i;
                float xv = (x[i] - ((k == arow) ? CM : 0.f)) * ih;
                if (arow >= 50 || k >= 52) xv = 0.f;
                const ushort h = bfrne(xv);
                sh[i] = (short)h;
                sl[i] = (short)bfrne(xv - bff(h));
            }
            Ah[ks] = sh; Al[ks] = sl;
        }
    }

    for (int e = tid; e < 16384; e += 512) ldsU[e] = 0;
    __syncthreads();
    const float cD = ccf.c[DEG];
    if (tid < 50) {  // u1 = cD * I into buf0 (swizzled)
        const ushort h = bfrne(cD);
        const ushort lo = bfrne(cD - bff(h));
        const int idx = tid * 64 + (tid ^ ((tid & 7) << 3));
        ldsU[idx] = h;
        ldsU[4096 + idx] = lo;
    }
    f32x4 u1r[2], u2r[2];
    #pragma unroll
    for (int t = 0; t < 2; ++t) {
        const int colR = (npair + t) * 16 + lr;
        #pragma unroll
        for (int r = 0; r < 4; ++r) {
            const int rowk = mrow * 16 + lg * 4 + r;
            u1r[t][r] = (rowk == colR && rowk < 50) ? cD : 0.f;
            u2r[t][r] = 0.f;
        }
    }
    __syncthreads();

    int cur = 0;
    for (int it = DEG - 1; it >= 0; --it) {
        const float ck = (it == 0) ? 0.5f * ccf.c[0] : ccf.c[it];
        const float two = (it == 0) ? 1.f : 2.f;
        const ushort* bufc = ldsU + cur * 8192;
        ushort* bufn = ldsU + (cur ^ 1) * 8192;

        f32x4 acc[2] = {(f32x4){0.f, 0.f, 0.f, 0.f}, (f32x4){0.f, 0.f, 0.f, 0.f}};
        short8 uh[2][2], ul[2][2];
        #pragma unroll
        for (int t = 0; t < 2; ++t) {
            const int R = (npair + t) * 16 + lr;
            const int swz = (R & 7) << 3;
            #pragma unroll
            for (int ks = 0; ks < 2; ++ks) {
                const int k0 = (ks * 32 + lg * 8) ^ swz;
                uh[t][ks] = *(const short8*)&bufc[R * 64 + k0];
                ul[t][ks] = *(const short8*)&bufc[4096 + R * 64 + k0];
            }
        }
        #pragma unroll
        for (int t = 0; t < 2; ++t) {
            #pragma unroll
            for (int ks = 0; ks < 2; ++ks) {
                acc[t] = __builtin_amdgcn_mfma_f32_16x16x32_bf16(Ah[ks], uh[t][ks], acc[t], 0, 0, 0);
                acc[t] = __builtin_amdgcn_mfma_f32_16x16x32_bf16(Ah[ks], ul[t][ks], acc[t], 0, 0, 0);
                acc[t] = __builtin_amdgcn_mfma_f32_16x16x32_bf16(Al[ks], uh[t][ks], acc[t], 0, 0, 0);
            }
        }
        #pragma unroll
        for (int t = 0; t < 2; ++t) {
            const int colR = (npair + t) * 16 + lr;
            f32x4 un;
            #pragma unroll
            for (int r = 0; r < 4; ++r) {
                const int rowk = mrow * 16 + lg * 4 + r;
                const float dd = (rowk == colR && rowk < 50) ? ck : 0.f;
                un[r] = two * acc[t][r] - u2r[t][r] + dd;
            }
            u2r[t] = u1r[t];
            u1r[t] = un;
            ushort h[4], lo[4];
            #pragma unroll
            for (int r = 0; r < 4; ++r) {
                h[r] = bfrne(un[r]);
                lo[r] = bfrne(un[r] - bff(h[r]));
            }
            const int swz = (colR & 7) << 3;
            const int k0 = (mrow * 16 + lg * 4) ^ swz;
            *(ushort4*)&bufn[colR * 64 + k0] = make_ushort4(h[0], h[1], h[2], h[3]);
            *(ushort4*)&bufn[4096 + colR * 64 + k0] = make_ushort4(lo[0], lo[1], lo[2], lo[3]);
        }
        __syncthreads();
        cur ^= 1;
    }

    #pragma unroll
    for (int t = 0; t < 2; ++t) {
        const int colR = (npair + t) * 16 + lr;
        if (colR < 50) {
            #pragma unroll
            for (int r = 0; r < 4; ++r) {
                const int rowk = mrow * 16 + lg * 4 + r;
                if (rowk < 50) Lf[rowk * 56 + colR] = u1r[t][r];
            }
        }
    }
    __syncthreads();

    float part[7] = {0, 0, 0, 0, 0, 0, 0};
    for (int e = tid; e < 2500; e += 512) {
        const float lv = Lf[(e / 50) * 56 + (e % 50)];
        #pragma unroll
        for (int n = 0; n < 7; ++n) part[n] = fmaf(lv, fc[e * 7 + n], part[n]);
    }
    #pragma unroll
    for (int n = 0; n < 7; ++n) red[tid * 7 + n] = part[n];
    __syncthreads();
    for (int s = 256; s > 0; s >>= 1) {
        if (tid < s) {
            #pragma unroll
            for (int n = 0; n < 7; ++n) red[tid * 7 + n] += red[(tid + s) * 7 + n];
        }
        __syncthreads();
    }
    if (tid < 7) out[b * 7 + tid] = red[tid];
}

extern "C" void kernel_launch(void* const* d_in, const int* in_sizes, int n_in,
                              void* d_out, int out_size, void* d_ws, size_t ws_size,
                              hipStream_t stream) {
    const float* X  = (const float*)d_in[0];
    const float* w1 = (const float*)d_in[1];
    const float* w2 = (const float*)d_in[2];
    const float* w3 = (const float*)d_in[3];
    const float* fc = (const float*)d_in[4];
    float* out = (float*)d_out;

    float* ws    = (float*)d_ws;
    float* T1    = ws;            // 400*100
    float* X3    = ws + 40000;    // 256*2600
    ushort* Wth  = (ushort*)(ws + 705600);  // 64*448 ushorts
    ushort* Wtl  = (ushort*)(ws + 719936);  // 64*448 ushorts

    // Chebyshev coefficients of log on [CM-CH, CM+CH]: host fp64 128-pt DCT
    ChebC cc;
    {
        double fv[128];
        for (int j = 0; j < 128; ++j)
            fv[j] = log(CM_D + CH_D * cos(PI_D * (j + 0.5) / 128.0));
        for (int t = 0; t < 32; ++t) {
            if (t <= DEG) {
                double s = 0.0;
                for (int j = 0; j < 128; ++j)
                    s += fv[j] * cos(PI_D * t * (j + 0.5) / 128.0);
                cc.c[t] = (float)(s * (2.0 / 128.0));
            } else cc.c[t] = 0.f;
        }
    }

    k_mm<<<(400 * 100 + 255) / 256, 256, 0, stream>>>(w1, w2, T1, 400, 200, 100);
    k_wprep<<<(64 * WKS + 255) / 256, 256, 0, stream>>>(T1, w3, Wth, Wtl);
    k_bimap<<<256, 512, 0, stream>>>(X, Wth, Wtl, X3);
    k_logcheb<<<256, 512, 0, stream>>>(X3, cc, fc, out);
}

// Round 12
// 138.730 us; speedup vs baseline: 1.7436x; 1.7436x over previous
//
#include <hip/hip_runtime.h>
#include <hip/hip_bf16.h>
#include <math.h>

// SPDNet collapsed: ReEig layers are no-ops (spectrum in [0.1, ~4.3] by
// Rayleigh interlacing through orthonormal-column BiMaps), so
//   X3 = (w1 w2 w3)^T X (w1 w2 w3);  out = vec(logm(X3)) @ fc
// logm via degree-28 Chebyshev matrix-Clenshaw on B=(X3-mI)/h, [0.0995,4.8].
// R12: k_bimap contiguous streaming WITHOUT the R11 spill (R11 counters:
//   +80MB reads/+60MB writes = pf[13] scratch spill at VGPR cap 128).
//   32-row tiles staged fp32 (pure float4 copy, pf[7]=28 VGPR), bf16x2
//   conversion moved to A-frag read (same total cvt count). Double-buffered
//   X [2][32][420] fp32 (pad cols 400..419 zeroed once; stride 420 -> 2-way
//   bank alias = free). Incremental phase-2 per row-tile from Yt[64][40]
//   h/l (10 KB). 2 barriers/iter, launch_bounds(512,2) -> VGPR cap 256.
//   k_logcheb / k_mm / k_wprep unchanged (verified R9/R10).
// ws layout (floats): T1 @0 (40000), X3 @40000 (665600),
//   Wth @705600 (ushort[64*448]), Wtl @719936. Total ~2.94 MB.

#define CM 2.44975f
#define CH 2.35025f
#define CM_D 2.44975
#define CH_D 2.35025
#define DEG 28
#define PI_D 3.14159265358979323846
#define XST 420  // X LDS row stride (floats)
#define YS 40    // Yt LDS row stride (ushorts)
#define WKS 448  // Wth/Wtl k stride

typedef __attribute__((ext_vector_type(8))) short short8;
typedef __attribute__((ext_vector_type(4))) float f32x4;

struct ChebC { float c[32]; };

__device__ __forceinline__ ushort bfrne(float x) {
    return __builtin_bit_cast(unsigned short, __float2bfloat16(x));
}
__device__ __forceinline__ float bff(ushort h) {
    return __uint_as_float(((unsigned)h) << 16);
}

__global__ void k_mm(const float* __restrict__ A, const float* __restrict__ B,
                     float* __restrict__ C, int M, int K, int N) {
    int e = blockIdx.x * blockDim.x + threadIdx.x;
    if (e >= M * N) return;
    int r = e / N, c = e % N;
    float acc = 0.f;
    for (int k = 0; k < K; ++k) acc = fmaf(A[r * K + k], B[k * N + c], acc);
    C[e] = acc;
}

// Fused: W = T1 @ w3 (400x100 @ 100x50), transposed + bf16x2 split.
// Wth/Wtl[64][448] c-major, zeros outside [50][400].
__global__ void k_wprep(const float* __restrict__ T1, const float* __restrict__ w3,
                        ushort* __restrict__ Wth, ushort* __restrict__ Wtl) {
    int e = blockIdx.x * blockDim.x + threadIdx.x;
    if (e >= 64 * WKS) return;
    int c = e / WKS, k = e % WKS;
    float v = 0.f;
    if (c < 50 && k < 400)
        for (int j = 0; j < 100; ++j) v = fmaf(T1[k * 100 + j], w3[j * 50 + c], v);
    const ushort h = bfrne(v);
    Wth[e] = h;
    Wtl[e] = bfrne(v - bff(h));
}

// One 512-thread (8-wave) block per batch. MFMA bf16x2.
// Per 32-row tile rt (13 tiles, rows 400..415 zero-padded):
//   (a) issue contiguous loads of tile rt+1 into pf[7]
//   (b) phase1: Y_tile = Xtile @ W; wave=(m1=w>>2 in 0..1, n1=w&3); A-frags
//       cvt'd fp32->bf16 h/l on read; B-frags from L2-resident global Wth/Wtl
//   (d) Y D-frags -> Yt[64][40] bf16 h/l (transposed, i-local 0..31)
//   (f) phase2: X3 += W^T[:, i-range] @ Y_tile; wave does tiles (m2,n2),(m2+2,n2)
//   (g) pf -> other X buffer;  barriers only after (d) and (g).
// W zero k-pad kills pad rows; pad cols of X3 (50,51) become exact 0.
__global__ __launch_bounds__(512, 2) void k_bimap(const float* __restrict__ X,
                                                  const ushort* __restrict__ Wth,
                                                  const ushort* __restrict__ Wtl,
                                                  float* __restrict__ X3) {
    __shared__ float XL[2][32 * XST];  // 107520 B
    __shared__ ushort YtH[64 * YS];    // 5120 B
    __shared__ ushort YtL[64 * YS];    // 5120 B
    const int tid = threadIdx.x;
    const int w = tid >> 6, l = tid & 63;
    const int lr = l & 15, lg = l >> 4;
    const int b = blockIdx.x;
    const float* __restrict__ Xb = X + (size_t)b * 160000;

    const int m1 = w >> 2, n1 = w & 3;  // phase1 tile (rows m1*16+, cols n1*16+)
    const int m2 = w >> 2, n2 = w & 3;  // phase2 tiles (m2,n2) and (m2+2,n2)

    // zero pad cols 400..419 of both buffers (stage never writes them)
    for (int e = tid; e < 2 * 32 * 20; e += 512) {
        const int bu = e / 640, rr = (e % 640) / 20, c = 400 + (e % 20);
        XL[bu][rr * XST + c] = 0.f;
    }
    // prologue: load tile 0 (fully in-bounds), write buf0
    float4 pf[7];
    #pragma unroll
    for (int j = 0; j < 7; ++j) {
        const int e = tid + 512 * j;
        if (e < 3200) pf[j] = *(const float4*)(Xb + (size_t)e * 4);
    }
    #pragma unroll
    for (int j = 0; j < 7; ++j) {
        const int e = tid + 512 * j;
        if (e < 3200) *(float4*)&XL[0][(e / 100) * XST + (e % 100) * 4] = pf[j];
    }
    __syncthreads();

    f32x4 p2a = (f32x4){0.f, 0.f, 0.f, 0.f};
    f32x4 p2b = (f32x4){0.f, 0.f, 0.f, 0.f};

    for (int rt = 0; rt < 13; ++rt) {
        // (a) issue contiguous loads of tile rt+1 (zero-guarded tail)
        if (rt < 12) {
            const size_t gbase = (size_t)(rt + 1) * 32 * 400;
            #pragma unroll
            for (int j = 0; j < 7; ++j) {
                const int e = tid + 512 * j;
                if (e < 3200) {
                    const size_t gf = gbase + (size_t)e * 4;
                    pf[j] = (gf < 160000) ? *(const float4*)(Xb + gf)
                                          : make_float4(0.f, 0.f, 0.f, 0.f);
                }
            }
        }
        // (b) phase1: p1 = Xtile(rows m1*16+lr) @ W(cols n1*16+lr), K=416
        const float* __restrict__ Xc = XL[rt & 1];
        f32x4 p1 = (f32x4){0.f, 0.f, 0.f, 0.f};
        for (int ks = 0; ks < 13; ++ks) {
            const float* ap = &Xc[(m1 * 16 + lr) * XST + ks * 32 + lg * 8];
            const float4 fa = *(const float4*)ap;
            const float4 fb = *(const float4*)(ap + 4);
            const float fv[8] = {fa.x, fa.y, fa.z, fa.w, fb.x, fb.y, fb.z, fb.w};
            short8 Ah, Al;
            #pragma unroll
            for (int i = 0; i < 8; ++i) {
                const ushort h = bfrne(fv[i]);
                Ah[i] = (short)h;
                Al[i] = (short)bfrne(fv[i] - bff(h));
            }
            const int c = n1 * 16 + lr;
            const short8 Bh = *(const short8*)&Wth[c * WKS + ks * 32 + lg * 8];
            const short8 Bl = *(const short8*)&Wtl[c * WKS + ks * 32 + lg * 8];
            p1 = __builtin_amdgcn_mfma_f32_16x16x32_bf16(Ah, Bh, p1, 0, 0, 0);
            p1 = __builtin_amdgcn_mfma_f32_16x16x32_bf16(Ah, Bl, p1, 0, 0, 0);
            p1 = __builtin_amdgcn_mfma_f32_16x16x32_bf16(Al, Bh, p1, 0, 0, 0);
        }
        // (d) Yt write (Yt's previous readers passed last iter's final barrier)
        {
            const int c = n1 * 16 + lr;
            const int i0l = m1 * 16 + lg * 4;
            ushort h[4], lo[4];
            #pragma unroll
            for (int r = 0; r < 4; ++r) {
                h[r] = bfrne(p1[r]);
                lo[r] = bfrne(p1[r] - bff(h[r]));
            }
            *(ushort4*)&YtH[c * YS + i0l] = make_ushort4(h[0], h[1], h[2], h[3]);
            *(ushort4*)&YtL[c * YS + i0l] = make_ushort4(lo[0], lo[1], lo[2], lo[3]);
        }
        __syncthreads();  // Yt visible; all waves done with XL[rt&1]
        // (f) phase2: X3 += W^T[:, rt*32 .. +31] @ Y_tile
        {
            const int i0 = rt * 32;
            const short8 Bh2 = *(const short8*)&YtH[(n2 * 16 + lr) * YS + lg * 8];
            const short8 Bl2 = *(const short8*)&YtL[(n2 * 16 + lr) * YS + lg * 8];
            #pragma unroll
            for (int s = 0; s < 2; ++s) {
                const int mm = m2 + 2 * s;
                const short8 Ah2 = *(const short8*)&Wth[(mm * 16 + lr) * WKS + i0 + lg * 8];
                const short8 Al2 = *(const short8*)&Wtl[(mm * 16 + lr) * WKS + i0 + lg * 8];
                f32x4& pp = s ? p2b : p2a;
                pp = __builtin_amdgcn_mfma_f32_16x16x32_bf16(Ah2, Bh2, pp, 0, 0, 0);
                pp = __builtin_amdgcn_mfma_f32_16x16x32_bf16(Ah2, Bl2, pp, 0, 0, 0);
                pp = __builtin_amdgcn_mfma_f32_16x16x32_bf16(Al2, Bh2, pp, 0, 0, 0);
            }
        }
        // (g) drain pf into the other buffer
        if (rt < 12) {
            float* __restrict__ Xn = XL[(rt + 1) & 1];
            #pragma unroll
            for (int j = 0; j < 7; ++j) {
                const int e = tid + 512 * j;
                if (e < 3200) *(float4*)&Xn[(e / 100) * XST + (e % 100) * 4] = pf[j];
            }
        }
        __syncthreads();  // staged buf visible; Yt readers done
    }

    float* __restrict__ dst = X3 + (size_t)b * 2600;
    #pragma unroll
    for (int s = 0; s < 2; ++s) {
        const int mm = m2 + 2 * s;
        const f32x4 v = s ? p2b : p2a;
        const int cc = n2 * 16 + lr;
        if (cc < 52) {
            #pragma unroll
            for (int r = 0; r < 4; ++r) {
                const int rr2 = mm * 16 + lg * 4 + r;
                if (rr2 < 50) dst[rr2 * 52 + cc] = v[r];
            }
        }
    }
}

// One 512-thread (8-wave) block per batch: L = p_DEG(B), MFMA Clenshaw.
// (verified R9/R10 at absmax 1.2e-4; unchanged)
__global__ __launch_bounds__(512) void k_logcheb(const float* __restrict__ X3,
                                                 const ChebC ccf,
                                                 const float* __restrict__ fc,
                                                 float* __restrict__ out) {
    __shared__ ushort ldsU[16384];  // 2 bufs x 2 lvl x 4096 (32 KB)
    __shared__ float Lf[50 * 56];
    __shared__ float red[512 * 7];
    const int tid = threadIdx.x;
    const int w = tid >> 6, l = tid & 63;
    const int lr = l & 15, lg = l >> 4;
    const int b = blockIdx.x;
    const float* __restrict__ src = X3 + (size_t)b * 2600;

    const int mrow = w >> 1;
    const int npair = (w & 1) * 2;

    short8 Ah[2], Al[2];
    {
        const int arow = mrow * 16 + lr;
        const float ih = 1.f / CH;
        #pragma unroll
        for (int ks = 0; ks < 2; ++ks) {
            float x[8];
            #pragma unroll
            for (int hf = 0; hf < 2; ++hf) {
                const int k0 = ks * 32 + lg * 8 + hf * 4;
                float4 v = make_float4(0.f, 0.f, 0.f, 0.f);
                if (arow < 50 && k0 < 52)
                    v = *(const float4*)(src + arow * 52 + k0);
                x[hf * 4 + 0] = v.x; x[hf * 4 + 1] = v.y;
                x[hf * 4 + 2] = v.z; x[hf * 4 + 3] = v.w;
            }
            short8 sh, sl;
            #pragma unroll
            for (int i = 0; i < 8; ++i) {
                const int k = ks * 32 + lg * 8 + i;
                float xv = (x[i] - ((k == arow) ? CM : 0.f)) * ih;
                if (arow >= 50 || k >= 52) xv = 0.f;
                const ushort h = bfrne(xv);
                sh[i] = (short)h;
                sl[i] = (short)bfrne(xv - bff(h));
            }
            Ah[ks] = sh; Al[ks] = sl;
        }
    }

    for (int e = tid; e < 16384; e += 512) ldsU[e] = 0;
    __syncthreads();
    const float cD = ccf.c[DEG];
    if (tid < 50) {  // u1 = cD * I into buf0 (swizzled)
        const ushort h = bfrne(cD);
        const ushort lo = bfrne(cD - bff(h));
        const int idx = tid * 64 + (tid ^ ((tid & 7) << 3));
        ldsU[idx] = h;
        ldsU[4096 + idx] = lo;
    }
    f32x4 u1r[2], u2r[2];
    #pragma unroll
    for (int t = 0; t < 2; ++t) {
        const int colR = (npair + t) * 16 + lr;
        #pragma unroll
        for (int r = 0; r < 4; ++r) {
            const int rowk = mrow * 16 + lg * 4 + r;
            u1r[t][r] = (rowk == colR && rowk < 50) ? cD : 0.f;
            u2r[t][r] = 0.f;
        }
    }
    __syncthreads();

    int cur = 0;
    for (int it = DEG - 1; it >= 0; --it) {
        const float ck = (it == 0) ? 0.5f * ccf.c[0] : ccf.c[it];
        const float two = (it == 0) ? 1.f : 2.f;
        const ushort* bufc = ldsU + cur * 8192;
        ushort* bufn = ldsU + (cur ^ 1) * 8192;

        f32x4 acc[2] = {(f32x4){0.f, 0.f, 0.f, 0.f}, (f32x4){0.f, 0.f, 0.f, 0.f}};
        short8 uh[2][2], ul[2][2];
        #pragma unroll
        for (int t = 0; t < 2; ++t) {
            const int R = (npair + t) * 16 + lr;
            const int swz = (R & 7) << 3;
            #pragma unroll
            for (int ks = 0; ks < 2; ++ks) {
                const int k0 = (ks * 32 + lg * 8) ^ swz;
                uh[t][ks] = *(const short8*)&bufc[R * 64 + k0];
                ul[t][ks] = *(const short8*)&bufc[4096 + R * 64 + k0];
            }
        }
        #pragma unroll
        for (int t = 0; t < 2; ++t) {
            #pragma unroll
            for (int ks = 0; ks < 2; ++ks) {
                acc[t] = __builtin_amdgcn_mfma_f32_16x16x32_bf16(Ah[ks], uh[t][ks], acc[t], 0, 0, 0);
                acc[t] = __builtin_amdgcn_mfma_f32_16x16x32_bf16(Ah[ks], ul[t][ks], acc[t], 0, 0, 0);
                acc[t] = __builtin_amdgcn_mfma_f32_16x16x32_bf16(Al[ks], uh[t][ks], acc[t], 0, 0, 0);
            }
        }
        #pragma unroll
        for (int t = 0; t < 2; ++t) {
            const int colR = (npair + t) * 16 + lr;
            f32x4 un;
            #pragma unroll
            for (int r = 0; r < 4; ++r) {
                const int rowk = mrow * 16 + lg * 4 + r;
                const float dd = (rowk == colR && rowk < 50) ? ck : 0.f;
                un[r] = two * acc[t][r] - u2r[t][r] + dd;
            }
            u2r[t] = u1r[t];
            u1r[t] = un;
            ushort h[4], lo[4];
            #pragma unroll
            for (int r = 0; r < 4; ++r) {
                h[r] = bfrne(un[r]);
                lo[r] = bfrne(un[r] - bff(h[r]));
            }
            const int swz = (colR & 7) << 3;
            const int k0 = (mrow * 16 + lg * 4) ^ swz;
            *(ushort4*)&bufn[colR * 64 + k0] = make_ushort4(h[0], h[1], h[2], h[3]);
            *(ushort4*)&bufn[4096 + colR * 64 + k0] = make_ushort4(lo[0], lo[1], lo[2], lo[3]);
        }
        __syncthreads();
        cur ^= 1;
    }

    #pragma unroll
    for (int t = 0; t < 2; ++t) {
        const int colR = (npair + t) * 16 + lr;
        if (colR < 50) {
            #pragma unroll
            for (int r = 0; r < 4; ++r) {
                const int rowk = mrow * 16 + lg * 4 + r;
                if (rowk < 50) Lf[rowk * 56 + colR] = u1r[t][r];
            }
        }
    }
    __syncthreads();

    float part[7] = {0, 0, 0, 0, 0, 0, 0};
    for (int e = tid; e < 2500; e += 512) {
        const float lv = Lf[(e / 50) * 56 + (e % 50)];
        #pragma unroll
        for (int n = 0; n < 7; ++n) part[n] = fmaf(lv, fc[e * 7 + n], part[n]);
    }
    #pragma unroll
    for (int n = 0; n < 7; ++n) red[tid * 7 + n] = part[n];
    __syncthreads();
    for (int s = 256; s > 0; s >>= 1) {
        if (tid < s) {
            #pragma unroll
            for (int n = 0; n < 7; ++n) red[tid * 7 + n] += red[(tid + s) * 7 + n];
        }
        __syncthreads();
    }
    if (tid < 7) out[b * 7 + tid] = red[tid];
}

extern "C" void kernel_launch(void* const* d_in, const int* in_sizes, int n_in,
                              void* d_out, int out_size, void* d_ws, size_t ws_size,
                              hipStream_t stream) {
    const float* X  = (const float*)d_in[0];
    const float* w1 = (const float*)d_in[1];
    const float* w2 = (const float*)d_in[2];
    const float* w3 = (const float*)d_in[3];
    const float* fc = (const float*)d_in[4];
    float* out = (float*)d_out;

    float* ws    = (float*)d_ws;
    float* T1    = ws;            // 400*100
    float* X3    = ws + 40000;    // 256*2600
    ushort* Wth  = (ushort*)(ws + 705600);  // 64*448 ushorts
    ushort* Wtl  = (ushort*)(ws + 719936);  // 64*448 ushorts

    // Chebyshev coefficients of log on [CM-CH, CM+CH]: host fp64 128-pt DCT
    ChebC cc;
    {
        double fv[128];
        for (int j = 0; j < 128; ++j)
            fv[j] = log(CM_D + CH_D * cos(PI_D * (j + 0.5) / 128.0));
        for (int t = 0; t < 32; ++t) {
            if (t <= DEG) {
                double s = 0.0;
                for (int j = 0; j < 128; ++j)
                    s += fv[j] * cos(PI_D * t * (j + 0.5) / 128.0);
                cc.c[t] = (float)(s * (2.0 / 128.0));
            } else cc.c[t] = 0.f;
        }
    }

    k_mm<<<(400 * 100 + 255) / 256, 256, 0, stream>>>(w1, w2, T1, 400, 200, 100);
    k_wprep<<<(64 * WKS + 255) / 256, 256, 0, stream>>>(T1, w3, Wth, Wtl);
    k_bimap<<<256, 512, 0, stream>>>(X, Wth, Wtl, X3);
    k_logcheb<<<256, 512, 0, stream>>>(X3, cc, fc, out);
}

// Round 13
// 128.333 us; speedup vs baseline: 1.8848x; 1.0810x over previous
//
#include <hip/hip_runtime.h>
#include <hip/hip_bf16.h>
#include <math.h>

// SPDNet collapsed: ReEig layers are no-ops (spectrum in [0.1, ~4.3] by
// Rayleigh interlacing through orthonormal-column BiMaps), so
//   X3 = (w1 w2 w3)^T X (w1 w2 w3);  out = vec(logm(X3)) @ fc
// logm via degree-28 Chebyshev matrix-Clenshaw on B=(X3-mI)/h, [0.0995,4.8].
// R13: kill forced vmcnt drains in k_bimap. Two mechanisms found (R10==R12
//   at ~1.8 TB/s, all pipes idle): (1) __syncthreads emits s_waitcnt vmcnt(0)
//   before s_barrier -> prefetch drained 2x/tile; (2) vmcnt is IN-ORDER, so
//   phase-1's per-ks GLOBAL W-fragment reads force-drained the older X
//   prefetch at first use. Fix: W (h+l) resident in LDS (no global loads in
//   the loop except the 7 pf loads) + raw "lgkmcnt(0); s_barrier" barriers
//   (pf targets private registers -> no visibility needed across barrier).
//   X tile single-buffered [32][420] fp32; tiling/math identical to R12.
// ws layout (floats): T1 @0 (40000), X3 @40000 (665600),
//   Wth @705600 (ushort[64*448]), Wtl @719936. Total ~2.94 MB.

#define CM 2.44975f
#define CH 2.35025f
#define CM_D 2.44975
#define CH_D 2.35025
#define DEG 28
#define PI_D 3.14159265358979323846
#define XST 420  // X LDS row stride (floats); 420%32=4 -> 2-way alias (free)
#define WLS 424  // W LDS row stride (ushorts); 212 dw %32=20 -> 2-way (free)
#define YS 40    // Yt LDS row stride (ushorts)
#define WKS 448  // global Wth/Wtl k stride

typedef __attribute__((ext_vector_type(8))) short short8;
typedef __attribute__((ext_vector_type(4))) float f32x4;

struct ChebC { float c[32]; };

__device__ __forceinline__ ushort bfrne(float x) {
    return __builtin_bit_cast(unsigned short, __float2bfloat16(x));
}
__device__ __forceinline__ float bff(ushort h) {
    return __uint_as_float(((unsigned)h) << 16);
}
// Barrier that does NOT drain vmcnt: LDS ops must complete (lgkmcnt), but
// outstanding global loads into private registers may stay in flight.
__device__ __forceinline__ void bar_lds() {
    asm volatile("s_waitcnt lgkmcnt(0)\n\ts_barrier" ::: "memory");
}

__global__ void k_mm(const float* __restrict__ A, const float* __restrict__ B,
                     float* __restrict__ C, int M, int K, int N) {
    int e = blockIdx.x * blockDim.x + threadIdx.x;
    if (e >= M * N) return;
    int r = e / N, c = e % N;
    float acc = 0.f;
    for (int k = 0; k < K; ++k) acc = fmaf(A[r * K + k], B[k * N + c], acc);
    C[e] = acc;
}

// Fused: W = T1 @ w3 (400x100 @ 100x50), transposed + bf16x2 split.
// Wth/Wtl[64][448] c-major, zeros outside [50][400].
__global__ void k_wprep(const float* __restrict__ T1, const float* __restrict__ w3,
                        ushort* __restrict__ Wth, ushort* __restrict__ Wtl) {
    int e = blockIdx.x * blockDim.x + threadIdx.x;
    if (e >= 64 * WKS) return;
    int c = e / WKS, k = e % WKS;
    float v = 0.f;
    if (c < 50 && k < 400)
        for (int j = 0; j < 100; ++j) v = fmaf(T1[k * 100 + j], w3[j * 50 + c], v);
    const ushort h = bfrne(v);
    Wth[e] = h;
    Wtl[e] = bfrne(v - bff(h));
}

// One 512-thread (8-wave) block per batch. MFMA bf16x2.
// Prologue: W rows 0..51 (k 0..415) -> LDS h/l; X tile0 staged.
// Per 32-row tile rt (13 tiles):
//   (a) issue 7 contiguous float4 loads of tile rt+1 (ONLY vmem in loop)
//   (b) phase1: Y_tile = Xtile @ W; wave=(m1=w>>2, n1=w&3); A cvt'd on read;
//       B-frags from LDS W (lanes with col>=52 use zero frags via exec mask)
//   (d) Y D-frags -> Yt[64][40] bf16 h/l;  BAR(lgkm)
//   (f) phase2: X3 += W^T[:, rt*32..+31] @ Y_tile (A from LDS W, rows>=52 zero)
//   (g) drain pf -> XL (compiler-inserted vmcnt wait lands HERE, after a full
//       iteration of overlap);  BAR(lgkm)
__global__ __launch_bounds__(512, 2) void k_bimap(const float* __restrict__ X,
                                                  const ushort* __restrict__ Wth,
                                                  const ushort* __restrict__ Wtl,
                                                  float* __restrict__ X3) {
    __shared__ float  XL[32 * XST];   // 53760 B
    __shared__ ushort WhL[52 * WLS];  // 44096 B
    __shared__ ushort WlL[52 * WLS];  // 44096 B
    __shared__ ushort YtH[64 * YS];   // 5120 B
    __shared__ ushort YtL[64 * YS];   // 5120 B   total 152192 B
    const int tid = threadIdx.x;
    const int w = tid >> 6, l = tid & 63;
    const int lr = l & 15, lg = l >> 4;
    const int b = blockIdx.x;
    const float* __restrict__ Xb = X + (size_t)b * 160000;
    const int m1 = w >> 2, n1 = w & 3;

    // prologue: W -> LDS (global rows have zeros at k>=400, rows>=50)
    for (int e = tid; e < 52 * 52; e += 512) {
        const int r = e / 52, k8 = (e % 52) * 8;
        *(short8*)&WhL[r * WLS + k8] = *(const short8*)&Wth[r * WKS + k8];
        *(short8*)&WlL[r * WLS + k8] = *(const short8*)&Wtl[r * WKS + k8];
    }
    // zero X pad cols 400..415 (staging writes cols 0..399 only)
    for (int e = tid; e < 32 * 16; e += 512)
        XL[(e / 16) * XST + 400 + (e % 16)] = 0.f;
    // stage tile 0 (rows 0..31, fully in-bounds)
    #pragma unroll
    for (int j = 0; j < 7; ++j) {
        const int e = tid + 512 * j;
        if (e < 3200)
            *(float4*)&XL[(e / 100) * XST + (e % 100) * 4] =
                *(const float4*)(Xb + (size_t)e * 4);
    }
    bar_lds();

    const int c1 = n1 * 16 + lr;      // phase1 Y-col / Yt row (0..63)
    const bool v1 = c1 < 52;
    f32x4 p2a = (f32x4){0.f, 0.f, 0.f, 0.f};
    f32x4 p2b = (f32x4){0.f, 0.f, 0.f, 0.f};
    float4 pf[7];

    for (int rt = 0; rt < 13; ++rt) {
        // (a) issue next-tile loads (private registers; stay in flight)
        if (rt < 12) {
            const size_t gbase = (size_t)(rt + 1) * 12800;
            #pragma unroll
            for (int j = 0; j < 7; ++j) {
                const int e = tid + 512 * j;
                if (e < 3200) {
                    const size_t gf = gbase + (size_t)e * 4;
                    pf[j] = (gf < 160000) ? *(const float4*)(Xb + gf)
                                          : make_float4(0.f, 0.f, 0.f, 0.f);
                }
            }
        }
        // (b) phase1: p1 = Xrows(m1*16+lr) @ Wcols(c1), K=416, all LDS
        f32x4 p1 = (f32x4){0.f, 0.f, 0.f, 0.f};
        for (int ks = 0; ks < 13; ++ks) {
            const int ko = ks * 32 + lg * 8;
            const float* ap = &XL[(m1 * 16 + lr) * XST + ko];
            const float4 fa = *(const float4*)ap;
            const float4 fb = *(const float4*)(ap + 4);
            const float fv[8] = {fa.x, fa.y, fa.z, fa.w, fb.x, fb.y, fb.z, fb.w};
            short8 Ah, Al;
            #pragma unroll
            for (int i = 0; i < 8; ++i) {
                const ushort h = bfrne(fv[i]);
                Ah[i] = (short)h;
                Al[i] = (short)bfrne(fv[i] - bff(h));
            }
            short8 Bh = {0, 0, 0, 0, 0, 0, 0, 0};
            short8 Bl = {0, 0, 0, 0, 0, 0, 0, 0};
            if (v1) {  // exec-masked; invalid lanes keep zero fragments
                Bh = *(const short8*)&WhL[c1 * WLS + ko];
                Bl = *(const short8*)&WlL[c1 * WLS + ko];
            }
            p1 = __builtin_amdgcn_mfma_f32_16x16x32_bf16(Ah, Bh, p1, 0, 0, 0);
            p1 = __builtin_amdgcn_mfma_f32_16x16x32_bf16(Ah, Bl, p1, 0, 0, 0);
            p1 = __builtin_amdgcn_mfma_f32_16x16x32_bf16(Al, Bh, p1, 0, 0, 0);
        }
        // (d) Yt write (rows c1; i-local m1*16+lg*4)
        {
            const int i0l = m1 * 16 + lg * 4;
            ushort h[4], lo[4];
            #pragma unroll
            for (int r = 0; r < 4; ++r) {
                h[r] = bfrne(p1[r]);
                lo[r] = bfrne(p1[r] - bff(h[r]));
            }
            *(ushort4*)&YtH[c1 * YS + i0l] = make_ushort4(h[0], h[1], h[2], h[3]);
            *(ushort4*)&YtL[c1 * YS + i0l] = make_ushort4(lo[0], lo[1], lo[2], lo[3]);
        }
        bar_lds();  // Yt visible; all phase1 XL readers done
        // (f) phase2: X3 += W^T[:, rt*32 .. +31] @ Y_tile (all LDS)
        {
            const int i0 = rt * 32 + lg * 8;
            const short8 Bh2 = *(const short8*)&YtH[c1 * YS + lg * 8];
            const short8 Bl2 = *(const short8*)&YtL[c1 * YS + lg * 8];
            #pragma unroll
            for (int s = 0; s < 2; ++s) {
                const int ra = (m1 + 2 * s) * 16 + lr;
                short8 Ah2 = {0, 0, 0, 0, 0, 0, 0, 0};
                short8 Al2 = {0, 0, 0, 0, 0, 0, 0, 0};
                if (ra < 52) {
                    Ah2 = *(const short8*)&WhL[ra * WLS + i0];
                    Al2 = *(const short8*)&WlL[ra * WLS + i0];
                }
                f32x4& pp = s ? p2b : p2a;
                pp = __builtin_amdgcn_mfma_f32_16x16x32_bf16(Ah2, Bh2, pp, 0, 0, 0);
                pp = __builtin_amdgcn_mfma_f32_16x16x32_bf16(Ah2, Bl2, pp, 0, 0, 0);
                pp = __builtin_amdgcn_mfma_f32_16x16x32_bf16(Al2, Bh2, pp, 0, 0, 0);
            }
        }
        // (g) drain pf into XL (vmcnt wait inserted here by compiler)
        if (rt < 12) {
            #pragma unroll
            for (int j = 0; j < 7; ++j) {
                const int e = tid + 512 * j;
                if (e < 3200)
                    *(float4*)&XL[(e / 100) * XST + (e % 100) * 4] = pf[j];
            }
        }
        bar_lds();  // staged tile visible; Yt readers done before next write
    }

    float* __restrict__ dst = X3 + (size_t)b * 2600;
    #pragma unroll
    for (int s = 0; s < 2; ++s) {
        const int mm = m1 + 2 * s;
        const f32x4 v = s ? p2b : p2a;
        const int cc = n1 * 16 + lr;
        if (cc < 52) {
            #pragma unroll
            for (int r = 0; r < 4; ++r) {
                const int rr2 = mm * 16 + lg * 4 + r;
                if (rr2 < 50) dst[rr2 * 52 + cc] = v[r];
            }
        }
    }
}

// One 512-thread (8-wave) block per batch: L = p_DEG(B), MFMA Clenshaw.
// (verified R9/R10/R12 at absmax 1.2e-4; unchanged)
__global__ __launch_bounds__(512) void k_logcheb(const float* __restrict__ X3,
                                                 const ChebC ccf,
                                                 const float* __restrict__ fc,
                                                 float* __restrict__ out) {
    __shared__ ushort ldsU[16384];  // 2 bufs x 2 lvl x 4096 (32 KB)
    __shared__ float Lf[50 * 56];
    __shared__ float red[512 * 7];
    const int tid = threadIdx.x;
    const int w = tid >> 6, l = tid & 63;
    const int lr = l & 15, lg = l >> 4;
    const int b = blockIdx.x;
    const float* __restrict__ src = X3 + (size_t)b * 2600;

    const int mrow = w >> 1;
    const int npair = (w & 1) * 2;

    short8 Ah[2], Al[2];
    {
        const int arow = mrow * 16 + lr;
        const float ih = 1.f / CH;
        #pragma unroll
        for (int ks = 0; ks < 2; ++ks) {
            float x[8];
            #pragma unroll
            for (int hf = 0; hf < 2; ++hf) {
                const int k0 = ks * 32 + lg * 8 + hf * 4;
                float4 v = make_float4(0.f, 0.f, 0.f, 0.f);
                if (arow < 50 && k0 < 52)
                    v = *(const float4*)(src + arow * 52 + k0);
                x[hf * 4 + 0] = v.x; x[hf * 4 + 1] = v.y;
                x[hf * 4 + 2] = v.z; x[hf * 4 + 3] = v.w;
            }
            short8 sh, sl;
            #pragma unroll
            for (int i = 0; i < 8; ++i) {
                const int k = ks * 32 + lg * 8 + i;
                float xv = (x[i] - ((k == arow) ? CM : 0.f)) * ih;
                if (arow >= 50 || k >= 52) xv = 0.f;
                const ushort h = bfrne(xv);
                sh[i] = (short)h;
                sl[i] = (short)bfrne(xv - bff(h));
            }
            Ah[ks] = sh; Al[ks] = sl;
        }
    }

    for (int e = tid; e < 16384; e += 512) ldsU[e] = 0;
    __syncthreads();
    const float cD = ccf.c[DEG];
    if (tid < 50) {  // u1 = cD * I into buf0 (swizzled)
        const ushort h = bfrne(cD);
        const ushort lo = bfrne(cD - bff(h));
        const int idx = tid * 64 + (tid ^ ((tid & 7) << 3));
        ldsU[idx] = h;
        ldsU[4096 + idx] = lo;
    }
    f32x4 u1r[2], u2r[2];
    #pragma unroll
    for (int t = 0; t < 2; ++t) {
        const int colR = (npair + t) * 16 + lr;
        #pragma unroll
        for (int r = 0; r < 4; ++r) {
            const int rowk = mrow * 16 + lg * 4 + r;
            u1r[t][r] = (rowk == colR && rowk < 50) ? cD : 0.f;
            u2r[t][r] = 0.f;
        }
    }
    __syncthreads();

    int cur = 0;
    for (int it = DEG - 1; it >= 0; --it) {
        const float ck = (it == 0) ? 0.5f * ccf.c[0] : ccf.c[it];
        const float two = (it == 0) ? 1.f : 2.f;
        const ushort* bufc = ldsU + cur * 8192;
        ushort* bufn = ldsU + (cur ^ 1) * 8192;

        f32x4 acc[2] = {(f32x4){0.f, 0.f, 0.f, 0.f}, (f32x4){0.f, 0.f, 0.f, 0.f}};
        short8 uh[2][2], ul[2][2];
        #pragma unroll
        for (int t = 0; t < 2; ++t) {
            const int R = (npair + t) * 16 + lr;
            const int swz = (R & 7) << 3;
            #pragma unroll
            for (int ks = 0; ks < 2; ++ks) {
                const int k0 = (ks * 32 + lg * 8) ^ swz;
                uh[t][ks] = *(const short8*)&bufc[R * 64 + k0];
                ul[t][ks] = *(const short8*)&bufc[4096 + R * 64 + k0];
            }
        }
        #pragma unroll
        for (int t = 0; t < 2; ++t) {
            #pragma unroll
            for (int ks = 0; ks < 2; ++ks) {
                acc[t] = __builtin_amdgcn_mfma_f32_16x16x32_bf16(Ah[ks], uh[t][ks], acc[t], 0, 0, 0);
                acc[t] = __builtin_amdgcn_mfma_f32_16x16x32_bf16(Ah[ks], ul[t][ks], acc[t], 0, 0, 0);
                acc[t] = __builtin_amdgcn_mfma_f32_16x16x32_bf16(Al[ks], uh[t][ks], acc[t], 0, 0, 0);
            }
        }
        #pragma unroll
        for (int t = 0; t < 2; ++t) {
            const int colR = (npair + t) * 16 + lr;
            f32x4 un;
            #pragma unroll
            for (int r = 0; r < 4; ++r) {
                const int rowk = mrow * 16 + lg * 4 + r;
                const float dd = (rowk == colR && rowk < 50) ? ck : 0.f;
                un[r] = two * acc[t][r] - u2r[t][r] + dd;
            }
            u2r[t] = u1r[t];
            u1r[t] = un;
            ushort h[4], lo[4];
            #pragma unroll
            for (int r = 0; r < 4; ++r) {
                h[r] = bfrne(un[r]);
                lo[r] = bfrne(un[r] - bff(h[r]));
            }
            const int swz = (colR & 7) << 3;
            const int k0 = (mrow * 16 + lg * 4) ^ swz;
            *(ushort4*)&bufn[colR * 64 + k0] = make_ushort4(h[0], h[1], h[2], h[3]);
            *(ushort4*)&bufn[4096 + colR * 64 + k0] = make_ushort4(lo[0], lo[1], lo[2], lo[3]);
        }
        __syncthreads();
        cur ^= 1;
    }

    #pragma unroll
    for (int t = 0; t < 2; ++t) {
        const int colR = (npair + t) * 16 + lr;
        if (colR < 50) {
            #pragma unroll
            for (int r = 0; r < 4; ++r) {
                const int rowk = mrow * 16 + lg * 4 + r;
                if (rowk < 50) Lf[rowk * 56 + colR] = u1r[t][r];
            }
        }
    }
    __syncthreads();

    float part[7] = {0, 0, 0, 0, 0, 0, 0};
    for (int e = tid; e < 2500; e += 512) {
        const float lv = Lf[(e / 50) * 56 + (e % 50)];
        #pragma unroll
        for (int n = 0; n < 7; ++n) part[n] = fmaf(lv, fc[e * 7 + n], part[n]);
    }
    #pragma unroll
    for (int n = 0; n < 7; ++n) red[tid * 7 + n] = part[n];
    __syncthreads();
    for (int s = 256; s > 0; s >>= 1) {
        if (tid < s) {
            #pragma unroll
            for (int n = 0; n < 7; ++n) red[tid * 7 + n] += red[(tid + s) * 7 + n];
        }
        __syncthreads();
    }
    if (tid < 7) out[b * 7 + tid] = red[tid];
}

extern "C" void kernel_launch(void* const* d_in, const int* in_sizes, int n_in,
                              void* d_out, int out_size, void* d_ws, size_t ws_size,
                              hipStream_t stream) {
    const float* X  = (const float*)d_in[0];
    const float* w1 = (const float*)d_in[1];
    const float* w2 = (const float*)d_in[2];
    const float* w3 = (const float*)d_in[3];
    const float* fc = (const float*)d_in[4];
    float* out = (float*)d_out;

    float* ws    = (float*)d_ws;
    float* T1    = ws;            // 400*100
    float* X3    = ws + 40000;    // 256*2600
    ushort* Wth  = (ushort*)(ws + 705600);  // 64*448 ushorts
    ushort* Wtl  = (ushort*)(ws + 719936);  // 64*448 ushorts

    // Chebyshev coefficients of log on [CM-CH, CM+CH]: host fp64 128-pt DCT
    ChebC cc;
    {
        double fv[128];
        for (int j = 0; j < 128; ++j)
            fv[j] = log(CM_D + CH_D * cos(PI_D * (j + 0.5) / 128.0));
        for (int t = 0; t < 32; ++t) {
            if (t <= DEG) {
                double s = 0.0;
                for (int j = 0; j < 128; ++j)
                    s += fv[j] * cos(PI_D * t * (j + 0.5) / 128.0);
                cc.c[t] = (float)(s * (2.0 / 128.0));
            } else cc.c[t] = 0.f;
        }
    }

    k_mm<<<(400 * 100 + 255) / 256, 256, 0, stream>>>(w1, w2, T1, 400, 200, 100);
    k_wprep<<<(64 * WKS + 255) / 256, 256, 0, stream>>>(T1, w3, Wth, Wtl);
    k_bimap<<<256, 512, 0, stream>>>(X, Wth, Wtl, X3);
    k_logcheb<<<256, 512, 0, stream>>>(X3, cc, fc, out);
}